// Round 15
// baseline (1374.923 us; speedup 1.0000x reference)
//
#include <hip/hip_runtime.h>
#include <stdint.h>

#define TLEN 512
#define HDIM 512
#define DDIM 128
#define NCLS 10

typedef float f32x4 __attribute__((ext_vector_type(4)));
typedef short bf16x8 __attribute__((ext_vector_type(8)));

__device__ __forceinline__ unsigned short f2bf(float f) {
  union { float f; unsigned u; } v; v.f = f;
  return (unsigned short)((v.u + 0x7FFFu + ((v.u >> 16) & 1u)) >> 16);
}
__device__ __forceinline__ float bf2f(unsigned short h) {
  union { unsigned u; float f; } v; v.u = ((unsigned)h) << 16; return v.f;
}
__device__ __forceinline__ float sigm(float x) {
  return __builtin_amdgcn_rcpf(1.0f + __expf(-x));
}
__device__ __forceinline__ void ast16(unsigned short* p, unsigned short v) {
  __hip_atomic_store(p, v, __ATOMIC_RELAXED, __HIP_MEMORY_SCOPE_AGENT);
}
__device__ __forceinline__ void astd(unsigned* p, unsigned v) {
  __hip_atomic_store(p, v, __ATOMIC_RELAXED, __HIP_MEMORY_SCOPE_AGENT);
}

// agent-scope (MALL) batched 16B load — proven (R9/R11/R12/R13/R14 passed)
#define GLOAD_SC1(dst, addr) \
  asm volatile("global_load_dwordx4 %0, %1, off sc1" : "=&v"(dst) : "v"(addr))
#define VMWAIT() do { asm volatile("s_waitcnt vmcnt(0)" ::: "memory"); \
                      __builtin_amdgcn_sched_barrier(0); } while (0)

// ---------------- gate tables: G[g][v][h], g in {f,i,c(pre-sigmoided),o} ----
__global__ void k_gates(const float* __restrict__ emb,
                        const float* __restrict__ Wfx, const float* __restrict__ bf_,
                        const float* __restrict__ Wix, const float* __restrict__ bi_,
                        const float* __restrict__ Wcx, const float* __restrict__ bc_,
                        const float* __restrict__ Wox, const float* __restrict__ bo_,
                        float* __restrict__ G) {
  int tid = blockIdx.x * 256 + threadIdx.x;          // 0..6143
  int h = tid & (HDIM - 1);
  int v = (tid >> 9) % 3;
  int g = tid / (3 * HDIM);
  const float* W; const float* bb;
  if (g == 0)      { W = Wfx; bb = bf_; }
  else if (g == 1) { W = Wix; bb = bi_; }
  else if (g == 2) { W = Wcx; bb = bc_; }
  else             { W = Wox; bb = bo_; }
  const float* e = emb + v * DDIM;
  const float* w = W + h * DDIM;
  float s = bb[h];
  #pragma unroll 8
  for (int d = 0; d < DDIM; ++d) s += e[d] * w[d];
  if (g == 2) s = sigm(s);                           // pre-sigmoid the c-gate
  G[tid] = s;
}

// ---------------- weight pack: register-resident B-fragments ----------------
// pk2: [hs(8)][nt(4)][gate(2)][kt(16)][lane(64)][e(8)] bf16
__global__ void k_pack_fi(const float* __restrict__ Wfh, const float* __restrict__ Wih,
                          unsigned short* __restrict__ pk) {
  int tid = blockIdx.x * 256 + threadIdx.x;          // 0..65535
  int l  = tid & 63;
  int kt = (tid >> 6) & 15;
  int g  = (tid >> 10) & 1;
  int nt = (tid >> 11) & 3;
  int hs = (tid >> 13) & 7;
  int n  = hs * 64 + nt * 16 + (l & 15);
  int k0 = kt * 32 + (l >> 4) * 8;
  const float* src = (g ? Wih : Wfh) + n * HDIM + k0;
  unsigned short* dst = pk + (size_t)tid * 8;
  #pragma unroll
  for (int e = 0; e < 8; ++e) dst[e] = f2bf(src[e]);
}

// pko: [hs(8)][nt(4)][kt(16)][lane(64)][e(8)] bf16
__global__ void k_pack_o(const float* __restrict__ Woh, unsigned short* __restrict__ pk) {
  int tid = blockIdx.x * 256 + threadIdx.x;          // 0..32767
  int l  = tid & 63;
  int kt = (tid >> 6) & 15;
  int nt = (tid >> 10) & 3;
  int hs = (tid >> 12) & 7;
  int n  = hs * 64 + nt * 16 + (l & 15);
  int k0 = kt * 32 + (l >> 4) * 8;
  const float* src = Woh + n * HDIM + k0;
  unsigned short* dst = pk + (size_t)tid * 8;
  #pragma unroll
  for (int e = 0; e < 8; ++e) dst[e] = f2bf(src[e]);
}

// ---------------- scan: 512 WGs = 64 groups (M=4 rows) x 8 h-slices ---------
// R11's proven sc1 protocol with: single-lane flag poll (32 B/sample, kills
// the R13/R14 poll storm), 2 WGs/CU (independent chains overlap latency —
// tests per-WG vs per-CU ingest limit), chunk-major LDS (no bank conflicts).
// cbuf layout per (par,btg): [kt(16)][row(4)][64B] = 4 KB.
__global__ __launch_bounds__(256, 1)
void k_scan(const int* __restrict__ x, const float* __restrict__ G,
            const unsigned short* __restrict__ pk2,
            const unsigned short* __restrict__ pko,
            char* __restrict__ cbuf, unsigned* __restrict__ flg,
            unsigned short* __restrict__ hfin) {
  __shared__ float gts[12][68];
  __shared__ unsigned char xv[4][512];
  __shared__ uint4 lds_small[16][16];                // chunk-major A-frag share (4 KB)

  const int tid  = threadIdx.x;
  const int lane = tid & 63;
  const int w    = tid >> 6;                         // wave = nt (0..3)
  const int hs   = blockIdx.x & 7;                   // h-slice
  const int btg  = blockIdx.x >> 3;                  // batch-group 0..63 (4 rows)

  for (int jj = tid; jj < 12 * 64; jj += 256) {
    int gv = jj >> 6, c = jj & 63;
    gts[gv][c] = G[gv * HDIM + hs * 64 + c];
  }
  for (int jj = tid; jj < 4 * 512; jj += 256) {
    int r = jj >> 9, tt = jj & 511;
    xv[r][tt] = (unsigned char)x[(btg * 4 + r) * TLEN + tt];
  }
  for (int jj = tid; jj < 16 * 16; jj += 256)
    ((uint4*)lds_small)[jj] = uint4{0, 0, 0, 0};     // c_0 = 0

  bf16x8 wf[16], wi[16];
  {
    const bf16x8* ws = (const bf16x8*)pk2 + (size_t)((hs * 4 + w) * 2) * (16 * 64) + lane;
    #pragma unroll
    for (int kt = 0; kt < 16; ++kt) { wf[kt] = ws[kt * 64]; wi[kt] = ws[(16 + kt) * 64]; }
  }

  bf16x8 afr[16];
  #pragma unroll
  for (int kt = 0; kt < 16; ++kt) afr[kt] = bf16x8{0,0,0,0,0,0,0,0};  // c_0 = 0

  float cf[4] = {0.f, 0.f, 0.f, 0.f};
  const int coll = lane & 15;
  const int col  = w * 16 + coll;                    // 0..63 within slice
  const int gcol = hs * 64 + col;                    // global h col
  const int soff = (gcol >> 5) * 256 + (gcol & 31) * 2;   // + r*64 (row stride 64B)
  const bool act = (lane < 16);                      // rows 0..3 producers
  // consumer load geometry: 1 distinct 16B chunk per lane (4 KB/WG unique)
  const int ldkt = 4 * w + (lane >> 4);              // kt this lane fetches
  const int ldof = ldkt * 256 + ((lane >> 2) & 3) * 64 + (lane & 3) * 16;
  const int sidx = (lane & 3) * 4 + ((lane >> 2) & 3);    // chunk-major store idx
  const int ridx = (lane >> 4) * 4 + (lane & 3);          // consumer read idx
  const f32x4 zz = {0.f, 0.f, 0.f, 0.f};

  __syncthreads();

  for (int t = 0; t < TLEN - 1; ++t) {
    f32x4 af = zz, ai = zz;
    #pragma unroll
    for (int kt = 0; kt < 16; ++kt) {
      af = __builtin_amdgcn_mfma_f32_16x16x32_bf16(afr[kt], wf[kt], af, 0, 0, 0);
      ai = __builtin_amdgcn_mfma_f32_16x16x32_bf16(afr[kt], wi[kt], ai, 0, 0, 0);
    }
    const unsigned tg = (unsigned)(t + 1);
    const int par = (int)(tg & 1);
    char* dbase = cbuf + (size_t)(par * 64 + btg) * 4096;

    if (act) {
      #pragma unroll
      for (int r = 0; r < 4; ++r) {                  // rows 0..3 (rgrp==0)
        int vv = xv[r][t];
        float fg = sigm(af[r] + gts[0 + vv][col]);
        float ig = sigm(ai[r] + gts[3 + vv][col]);
        float sc = gts[6 + vv][col];                 // pre-sigmoided c-gate
        float cn = sc * ig + cf[r] * fg;
        cf[r] = cn;
        ast16((unsigned short*)(dbase + soff + r * 64), f2bf(cn));
      }
    }
    __syncthreads();                                 // data stores drained (vmcnt 0)

    unsigned* fl = flg + (par * 64 + btg) * 16;      // 64B line, dword per hs
    if (tid == 0) astd(fl + hs, tg);

    // ---- single-lane flag poll per wave (32 B/sample — no poll storm) ------
    if (lane == 0) {
      uint4 f0, f1;
      do { GLOAD_SC1(f0, (const char*)fl); GLOAD_SC1(f1, (const char*)fl + 16); VMWAIT(); }
      while (((f0.x ^ tg) | (f0.y ^ tg) | (f0.z ^ tg) | (f0.w ^ tg) |
              (f1.x ^ tg) | (f1.y ^ tg) | (f1.z ^ tg) | (f1.w ^ tg)) != 0u);
    }
    // whole wave proceeds once lane 0 exits the loop

    // ---- dedup'd data loads: 1 distinct 16B chunk per lane (one RT) --------
    uint4 q;
    GLOAD_SC1(q, dbase + ldof);
    VMWAIT();
    lds_small[ldkt][sidx] = q;
    __syncthreads();
    #pragma unroll
    for (int kt = 0; kt < 16; ++kt) {
      union { uint4 qq; bf16x8 v; } u;
      u.qq = lds_small[kt][ridx];
      afr[kt] = u.v;
    }
  }

  // ---- final step t = 511: f, i and o gates; h = tanh(c)*o -----------------
  {
    const int t = TLEN - 1;
    f32x4 af = zz, ai = zz, ao = zz;
    #pragma unroll
    for (int kt = 0; kt < 16; ++kt) {
      af = __builtin_amdgcn_mfma_f32_16x16x32_bf16(afr[kt], wf[kt], af, 0, 0, 0);
      ai = __builtin_amdgcn_mfma_f32_16x16x32_bf16(afr[kt], wi[kt], ai, 0, 0, 0);
    }
    bf16x8 wo[16];
    const bf16x8* os = (const bf16x8*)pko + (size_t)(hs * 4 + w) * (16 * 64) + lane;
    #pragma unroll
    for (int kt = 0; kt < 16; ++kt) wo[kt] = os[kt * 64];
    #pragma unroll
    for (int kt = 0; kt < 16; ++kt)
      ao = __builtin_amdgcn_mfma_f32_16x16x32_bf16(afr[kt], wo[kt], ao, 0, 0, 0);
    if (act) {
      #pragma unroll
      for (int r = 0; r < 4; ++r) {
        int vv = xv[r][t];
        float fg = sigm(af[r] + gts[0 + vv][col]);
        float ig = sigm(ai[r] + gts[3 + vv][col]);
        float sc = gts[6 + vv][col];
        float cn = sc * ig + cf[r] * fg;
        float og = sigm(ao[r] + gts[9 + vv][col]);
        float hv = tanhf(cn) * og;
        hfin[(btg * 4 + r) * HDIM + gcol] = f2bf(hv);
      }
    }
  }
}

// ---------------- classifier head + log_softmax: one wave per row -----------
__global__ __launch_bounds__(64)
void k_head(const unsigned short* __restrict__ hfin, const float* __restrict__ Wph,
            const float* __restrict__ bp, float* __restrict__ out) {
  const int b = blockIdx.x;
  const int lane = threadIdx.x;
  float acc[NCLS];
  #pragma unroll
  for (int c = 0; c < NCLS; ++c) acc[c] = 0.f;
  const unsigned short* hrow = hfin + (size_t)b * HDIM;
  for (int k = lane; k < HDIM; k += 64) {
    float hv = bf2f(hrow[k]);
    #pragma unroll
    for (int c = 0; c < NCLS; ++c) acc[c] += hv * Wph[c * HDIM + k];
  }
  #pragma unroll
  for (int c = 0; c < NCLS; ++c)
    #pragma unroll
    for (int off = 32; off > 0; off >>= 1)
      acc[c] += __shfl_down(acc[c], off, 64);
  if (lane == 0) {
    float p[NCLS]; float m = -1e30f;
    #pragma unroll
    for (int c = 0; c < NCLS; ++c) { p[c] = acc[c] + bp[c]; m = fmaxf(m, p[c]); }
    float s = 0.f;
    #pragma unroll
    for (int c = 0; c < NCLS; ++c) s += __expf(p[c] - m);
    const float ls = __logf(s);
    #pragma unroll
    for (int c = 0; c < NCLS; ++c) out[b * NCLS + c] = p[c] - m - ls;
  }
}

extern "C" void kernel_launch(void* const* d_in, const int* in_sizes, int n_in,
                              void* d_out, int out_size, void* d_ws, size_t ws_size,
                              hipStream_t stream) {
  const int*   x   = (const int*)d_in[0];
  const float* emb = (const float*)d_in[1];
  const float* Wfx = (const float*)d_in[2];
  const float* Wfh = (const float*)d_in[3];
  const float* bf_ = (const float*)d_in[4];
  const float* Wix = (const float*)d_in[5];
  const float* Wih = (const float*)d_in[6];
  const float* bi_ = (const float*)d_in[7];
  const float* Wox = (const float*)d_in[8];
  const float* Woh = (const float*)d_in[9];
  const float* bo_ = (const float*)d_in[10];
  const float* Wcx = (const float*)d_in[11];
  const float* bc_ = (const float*)d_in[12];
  const float* Wph = (const float*)d_in[13];
  const float* bp_ = (const float*)d_in[14];

  char* ws = (char*)d_ws;
  float*          G    = (float*)(ws);                      // 24 KB  @ 0
  unsigned*       flg  = (unsigned*)(ws + 24576);           // 8 KB   @ 24K
  unsigned short* hfin = (unsigned short*)(ws + 32768);     // 256 KB @ 32K
  char*           cbuf = (char*)(ws + 524288);              // 512 KB @ 512K (2 par x 64 btg x 4KB)
  unsigned short* pk2  = (unsigned short*)(ws + 1572864);   // 1 MB   @ 1.5M
  unsigned short* pko  = (unsigned short*)(ws + 2621440);   // 512 KB @ 2.5M

  hipMemsetAsync(flg, 0, 8192, stream);                     // fresh flags every call
  hipLaunchKernelGGL(k_gates,   dim3(24),  dim3(256), 0, stream,
                     emb, Wfx, bf_, Wix, bi_, Wcx, bc_, Wox, bo_, G);
  hipLaunchKernelGGL(k_pack_fi, dim3(256), dim3(256), 0, stream, Wfh, Wih, pk2);
  hipLaunchKernelGGL(k_pack_o,  dim3(128), dim3(256), 0, stream, Woh, pko);
  hipLaunchKernelGGL(k_scan,    dim3(512), dim3(256), 0, stream,
                     x, G, pk2, pko, cbuf, flg, hfin);
  hipLaunchKernelGGL(k_head,    dim3(256), dim3(64),  0, stream, hfin, Wph, bp_, (float*)d_out);
}

// Round 16
// 1260.269 us; speedup vs baseline: 1.0910x; 1.0910x over previous
//
#include <hip/hip_runtime.h>
#include <stdint.h>

#define TLEN 512
#define HDIM 512
#define DDIM 128
#define NCLS 10

typedef float f32x4 __attribute__((ext_vector_type(4)));
typedef short bf16x8 __attribute__((ext_vector_type(8)));

__device__ __forceinline__ unsigned short f2bf(float f) {
  union { float f; unsigned u; } v; v.f = f;
  return (unsigned short)((v.u + 0x7FFFu + ((v.u >> 16) & 1u)) >> 16);
}
__device__ __forceinline__ float bf2f(unsigned short h) {
  union { unsigned u; float f; } v; v.u = ((unsigned)h) << 16; return v.f;
}
__device__ __forceinline__ float sigm(float x) {
  return __builtin_amdgcn_rcpf(1.0f + __expf(-x));
}
__device__ __forceinline__ void ast16(unsigned short* p, unsigned short v) {
  __hip_atomic_store(p, v, __ATOMIC_RELAXED, __HIP_MEMORY_SCOPE_AGENT);
}
__device__ __forceinline__ void astd(unsigned* p, unsigned v) {
  __hip_atomic_store(p, v, __ATOMIC_RELAXED, __HIP_MEMORY_SCOPE_AGENT);
}
__device__ __forceinline__ unsigned aldd(const unsigned* p) {
  return __hip_atomic_load(p, __ATOMIC_RELAXED, __HIP_MEMORY_SCOPE_AGENT);
}

// agent-scope (MALL) batched 16B load — proven (R9/R11/R12/R13/R14/R15)
#define GLOAD_SC1(dst, addr) \
  asm volatile("global_load_dwordx4 %0, %1, off sc1" : "=&v"(dst) : "v"(addr))
#define VMWAIT() do { asm volatile("s_waitcnt vmcnt(0)" ::: "memory"); \
                      __builtin_amdgcn_sched_barrier(0); } while (0)

// ---------------- gate tables: G[g][v][h], g in {f,i,c(pre-sigmoided),o} ----
__global__ void k_gates(const float* __restrict__ emb,
                        const float* __restrict__ Wfx, const float* __restrict__ bf_,
                        const float* __restrict__ Wix, const float* __restrict__ bi_,
                        const float* __restrict__ Wcx, const float* __restrict__ bc_,
                        const float* __restrict__ Wox, const float* __restrict__ bo_,
                        float* __restrict__ G) {
  int tid = blockIdx.x * 256 + threadIdx.x;          // 0..6143
  int h = tid & (HDIM - 1);
  int v = (tid >> 9) % 3;
  int g = tid / (3 * HDIM);
  const float* W; const float* bb;
  if (g == 0)      { W = Wfx; bb = bf_; }
  else if (g == 1) { W = Wix; bb = bi_; }
  else if (g == 2) { W = Wcx; bb = bc_; }
  else             { W = Wox; bb = bo_; }
  const float* e = emb + v * DDIM;
  const float* w = W + h * DDIM;
  float s = bb[h];
  #pragma unroll 8
  for (int d = 0; d < DDIM; ++d) s += e[d] * w[d];
  if (g == 2) s = sigm(s);                           // pre-sigmoid the c-gate
  G[tid] = s;
}

// ---------------- weight pack: register-resident B-fragments ----------------
// pk2: [hs(8)][nt(4)][gate(2)][kt(16)][lane(64)][e(8)] bf16
__global__ void k_pack_fi(const float* __restrict__ Wfh, const float* __restrict__ Wih,
                          unsigned short* __restrict__ pk) {
  int tid = blockIdx.x * 256 + threadIdx.x;          // 0..65535
  int l  = tid & 63;
  int kt = (tid >> 6) & 15;
  int g  = (tid >> 10) & 1;
  int nt = (tid >> 11) & 3;
  int hs = (tid >> 13) & 7;
  int n  = hs * 64 + nt * 16 + (l & 15);
  int k0 = kt * 32 + (l >> 4) * 8;
  const float* src = (g ? Wih : Wfh) + n * HDIM + k0;
  unsigned short* dst = pk + (size_t)tid * 8;
  #pragma unroll
  for (int e = 0; e < 8; ++e) dst[e] = f2bf(src[e]);
}

// pko: [hs(8)][nt(4)][kt(16)][lane(64)][e(8)] bf16
__global__ void k_pack_o(const float* __restrict__ Woh, unsigned short* __restrict__ pk) {
  int tid = blockIdx.x * 256 + threadIdx.x;          // 0..32767
  int l  = tid & 63;
  int kt = (tid >> 6) & 15;
  int nt = (tid >> 10) & 3;
  int hs = (tid >> 12) & 7;
  int n  = hs * 64 + nt * 16 + (l & 15);
  int k0 = kt * 32 + (l >> 4) * 8;
  const float* src = Woh + n * HDIM + k0;
  unsigned short* dst = pk + (size_t)tid * 8;
  #pragma unroll
  for (int e = 0; e < 8; ++e) dst[e] = f2bf(src[e]);
}

// ---------------- scan: 128 WGs = 16 batch-tiles x 8 h-slices ---------------
// Minimal proven chain (R11 fallback path, de-duplicated):
//   act -> sc1 c-stores -> barrier(drain) -> flag store (own 64B line)
//   -> all-lane 4B flag poll (one RT/sample) -> batched sc1 data loads
//   -> LDS share -> barrier.
// flg layout: [par(2)][bt(16)][hs(8) x 64B line]  (producers hit distinct lines)
__global__ __launch_bounds__(256, 1)
void k_scan(const int* __restrict__ x, const float* __restrict__ G,
            const unsigned short* __restrict__ pk2,
            const unsigned short* __restrict__ pko,
            char* __restrict__ cbuf, unsigned* __restrict__ flg,
            unsigned short* __restrict__ hfin) {
  __shared__ float gts[12][68];
  __shared__ unsigned char xv[16][516];
  __shared__ uint4 lds_a[16][64];                    // A-frag share (16 KB)

  const int tid  = threadIdx.x;
  const int lane = tid & 63;
  const int w    = tid >> 6;                         // wave = nt (0..3)
  const int bt   = blockIdx.x & 15;
  const int hs   = blockIdx.x >> 4;

  for (int jj = tid; jj < 12 * 64; jj += 256) {
    int gv = jj >> 6, c = jj & 63;
    gts[gv][c] = G[gv * HDIM + hs * 64 + c];
  }
  for (int jj = tid; jj < 16 * TLEN; jj += 256) {
    int r = jj >> 9, tt = jj & (TLEN - 1);
    xv[r][tt] = (unsigned char)x[(bt * 16 + r) * TLEN + tt];
  }

  bf16x8 wf[16], wi[16];
  {
    const bf16x8* ws = (const bf16x8*)pk2 + (size_t)((hs * 4 + w) * 2) * (16 * 64) + lane;
    #pragma unroll
    for (int kt = 0; kt < 16; ++kt) { wf[kt] = ws[kt * 64]; wi[kt] = ws[(16 + kt) * 64]; }
  }

  bf16x8 afr[16];
  #pragma unroll
  for (int kt = 0; kt < 16; ++kt) afr[kt] = bf16x8{0,0,0,0,0,0,0,0};  // c_0 = 0

  float cf[4] = {0.f, 0.f, 0.f, 0.f};
  const int rgrp = (lane >> 4) * 4;                  // C/D row base (batch row)
  const int coll = lane & 15;                        // C/D col (within 16-tile)
  const int col  = w * 16 + coll;                    // h col within slice
  const int colb = (hs * 64 + col) * 2;              // byte offset within a row
  const int rowb = (lane & 15) * 1024 + (lane >> 4) * 16;
  const f32x4 zz = {0.f, 0.f, 0.f, 0.f};

  __syncthreads();

  for (int t = 0; t < TLEN - 1; ++t) {
    f32x4 af = zz, ai = zz;
    #pragma unroll
    for (int kt = 0; kt < 16; ++kt) {
      af = __builtin_amdgcn_mfma_f32_16x16x32_bf16(afr[kt], wf[kt], af, 0, 0, 0);
      ai = __builtin_amdgcn_mfma_f32_16x16x32_bf16(afr[kt], wi[kt], ai, 0, 0, 0);
    }
    const unsigned tg = (unsigned)(t + 1);
    const int par = (int)(tg & 1);
    char* dbase = cbuf + par * 262144 + bt * 16384;

    #pragma unroll
    for (int r = 0; r < 4; ++r) {
      int vv = xv[rgrp + r][t];
      float fg = sigm(af[r] + gts[0 + vv][col]);
      float ig = sigm(ai[r] + gts[3 + vv][col]);
      float sc = gts[6 + vv][col];                   // pre-sigmoided c-gate
      float cn = sc * ig + cf[r] * fg;
      cf[r] = cn;
      ast16((unsigned short*)(dbase + (rgrp + r) * 1024 + colb), f2bf(cn));
    }
    __syncthreads();                                 // data stores drained (vmcnt 0)

    // flag: own 64B line per (par,bt,hs) — no producer line contention
    unsigned* fl = flg + ((par * 16 + bt) * 8) * 16;
    if (tid == 0) astd(fl + hs * 16, tg);

    // all-lane 4B poll: lane i watches flag (i&7); one RT per sample, 256B/WG
    {
      const unsigned* myf = fl + (lane & 7) * 16;
      unsigned fv;
      do { fv = aldd(myf); } while (!__all(fv == tg));
    }

    // batched data loads: this wave's 4 kt quarters, full 64B lines per row
    const char* rb = dbase + rowb + (w << 8);
    uint4 q0, q1, q2, q3;
    GLOAD_SC1(q0, rb);       GLOAD_SC1(q1, rb + 64);
    GLOAD_SC1(q2, rb + 128); GLOAD_SC1(q3, rb + 192);
    VMWAIT();
    lds_a[(w << 2) | 0][lane] = q0;
    lds_a[(w << 2) | 1][lane] = q1;
    lds_a[(w << 2) | 2][lane] = q2;
    lds_a[(w << 2) | 3][lane] = q3;
    __syncthreads();
    #pragma unroll
    for (int kt = 0; kt < 16; ++kt) {
      union { uint4 q; bf16x8 v; } u;
      u.q = lds_a[kt][lane];
      afr[kt] = u.v;
    }
  }

  // ---- final step t = 511: f, i and o gates; h = tanh(c)*o -----------------
  {
    const int t = TLEN - 1;
    f32x4 af = zz, ai = zz, ao = zz;
    #pragma unroll
    for (int kt = 0; kt < 16; ++kt) {
      af = __builtin_amdgcn_mfma_f32_16x16x32_bf16(afr[kt], wf[kt], af, 0, 0, 0);
      ai = __builtin_amdgcn_mfma_f32_16x16x32_bf16(afr[kt], wi[kt], ai, 0, 0, 0);
    }
    bf16x8 wo[16];
    const bf16x8* os = (const bf16x8*)pko + (size_t)(hs * 4 + w) * (16 * 64) + lane;
    #pragma unroll
    for (int kt = 0; kt < 16; ++kt) wo[kt] = os[kt * 64];
    #pragma unroll
    for (int kt = 0; kt < 16; ++kt)
      ao = __builtin_amdgcn_mfma_f32_16x16x32_bf16(afr[kt], wo[kt], ao, 0, 0, 0);
    #pragma unroll
    for (int r = 0; r < 4; ++r) {
      int vv = xv[rgrp + r][t];
      float fg = sigm(af[r] + gts[0 + vv][col]);
      float ig = sigm(ai[r] + gts[3 + vv][col]);
      float sc = gts[6 + vv][col];
      float cn = sc * ig + cf[r] * fg;
      float og = sigm(ao[r] + gts[9 + vv][col]);
      float hv = tanhf(cn) * og;
      hfin[(bt * 16 + rgrp + r) * HDIM + hs * 64 + col] = f2bf(hv);
    }
  }
}

// ---------------- classifier head + log_softmax: one wave per row -----------
__global__ __launch_bounds__(64)
void k_head(const unsigned short* __restrict__ hfin, const float* __restrict__ Wph,
            const float* __restrict__ bp, float* __restrict__ out) {
  const int b = blockIdx.x;
  const int lane = threadIdx.x;
  float acc[NCLS];
  #pragma unroll
  for (int c = 0; c < NCLS; ++c) acc[c] = 0.f;
  const unsigned short* hrow = hfin + (size_t)b * HDIM;
  for (int k = lane; k < HDIM; k += 64) {
    float hv = bf2f(hrow[k]);
    #pragma unroll
    for (int c = 0; c < NCLS; ++c) acc[c] += hv * Wph[c * HDIM + k];
  }
  #pragma unroll
  for (int c = 0; c < NCLS; ++c)
    #pragma unroll
    for (int off = 32; off > 0; off >>= 1)
      acc[c] += __shfl_down(acc[c], off, 64);
  if (lane == 0) {
    float p[NCLS]; float m = -1e30f;
    #pragma unroll
    for (int c = 0; c < NCLS; ++c) { p[c] = acc[c] + bp[c]; m = fmaxf(m, p[c]); }
    float s = 0.f;
    #pragma unroll
    for (int c = 0; c < NCLS; ++c) s += __expf(p[c] - m);
    const float ls = __logf(s);
    #pragma unroll
    for (int c = 0; c < NCLS; ++c) out[b * NCLS + c] = p[c] - m - ls;
  }
}

extern "C" void kernel_launch(void* const* d_in, const int* in_sizes, int n_in,
                              void* d_out, int out_size, void* d_ws, size_t ws_size,
                              hipStream_t stream) {
  const int*   x   = (const int*)d_in[0];
  const float* emb = (const float*)d_in[1];
  const float* Wfx = (const float*)d_in[2];
  const float* Wfh = (const float*)d_in[3];
  const float* bf_ = (const float*)d_in[4];
  const float* Wix = (const float*)d_in[5];
  const float* Wih = (const float*)d_in[6];
  const float* bi_ = (const float*)d_in[7];
  const float* Wox = (const float*)d_in[8];
  const float* Woh = (const float*)d_in[9];
  const float* bo_ = (const float*)d_in[10];
  const float* Wcx = (const float*)d_in[11];
  const float* bc_ = (const float*)d_in[12];
  const float* Wph = (const float*)d_in[13];
  const float* bp_ = (const float*)d_in[14];

  char* ws = (char*)d_ws;
  float*          G    = (float*)(ws);                      // 24 KB  @ 0
  unsigned short* hfin = (unsigned short*)(ws + 32768);     // 256 KB @ 32K
  unsigned*       flg  = (unsigned*)(ws + 294912);          // 16 KB  @ 288K
  char*           cbuf = (char*)(ws + 524288);              // 512 KB @ 512K
  unsigned short* pk2  = (unsigned short*)(ws + 1572864);   // 1 MB   @ 1.5M
  unsigned short* pko  = (unsigned short*)(ws + 2621440);   // 512 KB @ 2.5M

  hipMemsetAsync(flg, 0, 16384, stream);                    // fresh flags every call
  hipLaunchKernelGGL(k_gates,   dim3(24),  dim3(256), 0, stream,
                     emb, Wfx, bf_, Wix, bi_, Wcx, bc_, Wox, bo_, G);
  hipLaunchKernelGGL(k_pack_fi, dim3(256), dim3(256), 0, stream, Wfh, Wih, pk2);
  hipLaunchKernelGGL(k_pack_o,  dim3(128), dim3(256), 0, stream, Woh, pko);
  hipLaunchKernelGGL(k_scan,    dim3(128), dim3(256), 0, stream,
                     x, G, pk2, pko, cbuf, flg, hfin);
  hipLaunchKernelGGL(k_head,    dim3(256), dim3(64),  0, stream, hfin, Wph, bp_, (float*)d_out);
}